// Round 9
// baseline (10198.425 us; speedup 1.0000x reference)
//
#include <hip/hip_runtime.h>
#include <hip/hip_bf16.h>
#include <stdint.h>

// LCA on MI355X, round 14. G-form in FP16. r12 (bf16 G) failed 0.1328; r13
// (diag-exact g, split-x b) failed 0.0781 -- remaining error attributed to
// bf16 quantization of the STORED Gram (residual form's effective Gram is the
// unrounded f32 MFMA product of bf16 w) and bf16 a. Fix: the whole G-path in
// f16 (mfma_f32_16x16x32_f16; C/D layout dtype-independent, m89/m101): w-f16,
// g=f16(w^T w - I) (diag subtracted in f32), a-f16, b from xh(f16)@w(f16) --
// every G-path quantization 8x tighter than bf16, strictly below the PASSING
// residual form's budget. Iteration: C=a@g; u+=0.01*(b-C-u); a=relu(u-0.3);
// one GEMM/iter, grid 64x16=1024 blocks (4/CU), NW=4, TBK=32.
// Memory: aP1 lives at d_out+0 (33.5MB; dead before final writes; fits bf16
// mode's 46.4MB), aP0 in ws. Tiers by ws_size: b-f32 (179.4MB) else b-f16
// (145.9MB; ws>=162.2 proven in r12) else residual fallback (9.39ms).

typedef __bf16 bf16_t;
typedef _Float16 f16_t;
typedef float f32x4 __attribute__((ext_vector_type(4)));
typedef __bf16 bf16x8 __attribute__((ext_vector_type(8)));
typedef _Float16 f16x8 __attribute__((ext_vector_type(8)));
typedef int int4v __attribute__((ext_vector_type(4)));

#define BM 128

template <typename ET>
static __device__ __forceinline__ f32x4 mfma16(int4v a, int4v b, f32x4 c) {
    if constexpr (__is_same(ET, bf16_t))
        return __builtin_amdgcn_mfma_f32_16x16x32_bf16(
            __builtin_bit_cast(bf16x8, a), __builtin_bit_cast(bf16x8, b), c, 0, 0, 0);
    else
        return __builtin_amdgcn_mfma_f32_16x16x32_f16(
            __builtin_bit_cast(f16x8, a), __builtin_bit_cast(f16x8, b), c, 0, 0, 0);
}

// async global->LDS, 16B/lane; LDS dest = wave-uniform base + lane*16.
static __device__ __forceinline__ void gl_lds16(const void* gp, void* lp) {
    auto g1 = (const __attribute__((address_space(1))) uint32_t*)(uintptr_t)gp;
    auto l3 = (__attribute__((address_space(3))) uint32_t*)(uintptr_t)lp;
    __builtin_amdgcn_global_load_lds(g1, l3, 16, 0, 0);
}

template <int N>
static __device__ __forceinline__ void vm_wait() {
    if constexpr (N == 0)      asm volatile("s_waitcnt vmcnt(0)" ::: "memory");
    else if constexpr (N == 2) asm volatile("s_waitcnt vmcnt(2)" ::: "memory");
    else if constexpr (N == 4) asm volatile("s_waitcnt vmcnt(4)" ::: "memory");
    else if constexpr (N == 6) asm volatile("s_waitcnt vmcnt(6)" ::: "memory");
    else if constexpr (N == 8) asm volatile("s_waitcnt vmcnt(8)" ::: "memory");
    else                       static_assert(N == 0, "unsupported vmcnt");
}

// LDS chunk-swizzle fold. CPR=8: row&7 (measured 0-conflict, r7).
// CPR=4: row&3 (r8: 3.67M cyc; the r10 alternative (row^row>>2)&3 was WORSE).
template <int CPR>
static __device__ __forceinline__ int foldf(int r) {
    if constexpr (CPR == 8) return r & 7;
    else                    return r & 3;
}

// flag=1 iff inputs are fp32 (sniff even halfwords of w: fp32 mantissa bits
// look like huge-exponent bf16s; real bf16 |w|<=1 has exp field <= 0x7f).
__global__ void sniff(const uint16_t* __restrict__ wh, int* __restrict__ flag) {
    __shared__ int cnt;
    if (threadIdx.x == 0) cnt = 0;
    __syncthreads();
    int c = 0;
    for (int t = threadIdx.x; t < 4096; t += 256) {
        uint16_t h = wh[(size_t)2 * t * 97];
        c += (((h >> 7) & 0xFF) >= 0x82);
    }
    atomicAdd(&cnt, c);
    __syncthreads();
    if (threadIdx.x == 0) flag[0] = (cnt > 256) ? 1 : 0;
}

__global__ void fill0(int4v* __restrict__ p, long n16) {
    long i = (long)blockIdx.x * 256 + threadIdx.x;
    if (i < n16) p[i] = (int4v){0, 0, 0, 0};
}

static __device__ __forceinline__ float ldin(const void* p, size_t i, int f) {
    return f ? ((const float*)p)[i] : (float)((const bf16_t*)p)[i];
}

// ---- bf16 builders (fallback path) ----
__global__ void build_w(const void* __restrict__ w, bf16_t* __restrict__ wT,
                        bf16_t* __restrict__ wB, const int* __restrict__ flag) {
    const int k = blockIdx.x * 256 + threadIdx.x;
    const int j = blockIdx.y;
    if (k >= 800) return;
    bf16_t v = (bf16_t)0.0f;
    if (k < 784) {
        v = (bf16_t)ldin(w, (size_t)k * 2048 + j, flag[0]);
        wB[(size_t)k * 2048 + j] = v;
    }
    wT[(size_t)j * 800 + k] = v;
}

// ---- f16 builders (G path) ----
__global__ void build_wh(const void* __restrict__ w, f16_t* __restrict__ wTh,
                         const int* __restrict__ flag) {
    const int k = blockIdx.x * 256 + threadIdx.x;   // pixel (pad 800)
    const int j = blockIdx.y;                       // latent
    if (k >= 800) return;
    f16_t v = (f16_t)0.0f;
    if (k < 784) v = (f16_t)ldin(w, (size_t)k * 2048 + j, flag[0]);
    wTh[(size_t)j * 800 + k] = v;
}

__global__ void build_wbh(const void* __restrict__ w, f16_t* __restrict__ wBh,
                          const int* __restrict__ flag) {
    const int j = blockIdx.x * 256 + threadIdx.x;   // latent
    const int p = blockIdx.y;                       // pixel
    if (j >= 2048) return;
    wBh[(size_t)p * 2048 + j] = (f16_t)ldin(w, (size_t)p * 2048 + j, flag[0]);
}

__global__ void build_xh(const void* __restrict__ x, f16_t* __restrict__ xh,
                         const int* __restrict__ flag) {
    const int k = blockIdx.x * 256 + threadIdx.x;   // pixel (pad 800)
    const int i = blockIdx.y;
    if (k >= 800) return;
    f16_t v = (f16_t)0.0f;
    if (k < 784) v = (f16_t)ldin(x, (size_t)i * 784 + k, flag[0]);
    xh[(size_t)i * 800 + k] = v;
}

// NT-GEMM  C[i,j] = sum_k A[i,k]*B[j,k].  Tile BM x BNT, K-step TBK, NW waves
// (wave grid 2 x NW/2; per-wave output 64 x BNT/(NW/2)). Element type ET.
// 2-phase double-buffered: stage tile t+1 via global_load_lds while computing
// tile t; counted s_waitcnt vmcnt(L) keeps next tile's loads in flight across
// the barrier. LDS chunk-XOR swizzle (chunk ^= foldf(row), 16B granularity)
// applied on the global source AND the ds_read address (linear LDS dest).
// MODE 0 (R):    r[gm,gn] = x[gm,gn] - C   (gn<N; x dtype per flag) [fallback]
// MODE 1 (STEP): uo=U; ao=relu(uo-.3); un=uo+.01*(C+ao-uo); U=un; a=relu(un-.3)
// MODE 2 (ETOUT):Out[gm,gn] = (ET)C  (gn<N)
// MODE 3 (GSTEP):uo=U; un=uo+0.01*(b - C - uo); U=un; Out=(ET)relu(un-.3)
//                (b at Xin, f32 if BF32 else ET; g has zero diag)
// MODE 4 (F32):  U[gm*ldo+gn] = C
// MODE 5 (GRAM): Out[gm,gn] = (ET)(C - (gm==gn))   -- g = w^T w - I
template <int MODE, bool CLAMPN, int BNT, int TBK, int NW,
          typename ET = bf16_t, bool BF32 = true>
__global__ __launch_bounds__(NW * 64, 4) void gemm_nt(
    const ET* __restrict__ A, const ET* __restrict__ B,
    int N, int K, int lda, int ldb,
    const void* __restrict__ Xin, float* __restrict__ U,
    ET* __restrict__ Out, int ldo, const int* __restrict__ flag)
{
    constexpr int THREADS = NW * 64;
    constexpr int NWN = NW / 2;            // wave-grid cols (2 rows of waves)
    constexpr int MT  = 4;                 // 16-row m-tiles per wave (BM/32)
    constexpr int NTW = BNT / (NWN * 16);  // 16-col n-tiles per wave
    constexpr int CPR = TBK / 8;           // 16B chunks per tile row
    constexpr int AL  = BM * CPR / THREADS;    // A staging insts per thread
    constexpr int BL  = BNT * CPR / THREADS;   // B staging insts per thread
    constexpr int L   = AL + BL;           // loads in flight per tile per wave
    constexpr int KH  = TBK / 32;          // k-halves per tile (MFMA K=32)
    static_assert(AL >= 1 && BL >= 1 && NTW >= 1, "geometry");

    __shared__ __align__(16) ET sA[2][BM * TBK];
    __shared__ __align__(16) ET sB[2][BNT * TBK];

    const int tid  = threadIdx.x;
    const int lane = tid & 63;
    const int wave = tid >> 6;
    const int wm   = wave / NWN;
    const int wn   = wave % NWN;
    const int bm   = blockIdx.x * BM;
    const int bn   = blockIdx.y * BNT;

    f32x4 acc[MT][NTW];
#pragma unroll
    for (int i = 0; i < MT; ++i)
#pragma unroll
        for (int j = 0; j < NTW; ++j) acc[i][j] = (f32x4){0.f, 0.f, 0.f, 0.f};

    // staging map: chunk c = l*THREADS+tid -> LDS row c/CPR, LDS chunk c%CPR,
    // LDS offset c*16B (linear). SOURCE chunk = (c%CPR) ^ foldf(row) so that
    // LDS[row][chunk] holds logical chunk (chunk ^ foldf(row)).
    const ET* gA[AL];
    const ET* gB[BL];
#pragma unroll
    for (int l = 0; l < AL; ++l) {
        const int c  = l * THREADS + tid;
        const int rL = c / CPR;
        const int sc = (c & (CPR - 1)) ^ foldf<CPR>(rL);
        gA[l] = A + (size_t)(bm + rL) * lda + sc * 8;
    }
#pragma unroll
    for (int l = 0; l < BL; ++l) {
        const int c  = l * THREADS + tid;
        const int rL = c / CPR;
        const int sc = (c & (CPR - 1)) ^ foldf<CPR>(rL);
        int rb = bn + rL;
        if (CLAMPN) rb = min(rb, N - 1);
        gB[l] = B + (size_t)rb * ldb + sc * 8;
    }

    auto stage = [&](int buf, int k0) {
#pragma unroll
        for (int l = 0; l < AL; ++l)
            gl_lds16(gA[l] + k0, &sA[buf][(size_t)(l * THREADS + tid) * 8]);
#pragma unroll
        for (int l = 0; l < BL; ++l)
            gl_lds16(gB[l] + k0, &sB[buf][(size_t)(l * THREADS + tid) * 8]);
    };

    const int mrow = lane & 15;
    const int q    = lane >> 4;
    // read-side swizzle: fragment rows are (mult of 16) + mrow, and foldf only
    // uses row bits [2:0] -> per-lane constant.
    const int swz = foldf<CPR>(mrow);
    const int qx  = q ^ (swz & 3);          // low 2 chunk bits
    const int ksw = swz >> 2;               // chunk bit 2 (CPR=8 only)

    stage(0, 0);
    int cur = 0;
    for (int k0 = 0; k0 < K; k0 += TBK) {
        if (k0 + TBK < K) {
            stage(cur ^ 1, k0 + TBK);   // next tile's DMA in flight across barrier
            vm_wait<L>();               // wait only for CURRENT tile's L loads
        } else {
            vm_wait<0>();               // epilogue drain
        }
        __builtin_amdgcn_s_barrier();   // all waves' DMA for buf[cur] landed
        asm volatile("" ::: "memory");  // don't hoist ds_reads above barrier

        int4v af[MT][KH], bv[NTW][KH];
        const ET* pa = &sA[cur][(wm * 64 + mrow) * TBK + qx * 8];
        const ET* pb = &sB[cur][(wn * (NTW * 16) + mrow) * TBK + qx * 8];
#pragma unroll
        for (int t = 0; t < MT; ++t)
#pragma unroll
            for (int kk = 0; kk < KH; ++kk)
                af[t][kk] = *(const int4v*)(pa + t * 16 * TBK + (kk ^ ksw) * 32);
#pragma unroll
        for (int t = 0; t < NTW; ++t)
#pragma unroll
            for (int kk = 0; kk < KH; ++kk)
                bv[t][kk] = *(const int4v*)(pb + t * 16 * TBK + (kk ^ ksw) * 32);
#pragma unroll
        for (int kk = 0; kk < KH; ++kk)       // logical k-order unchanged
#pragma unroll
            for (int mt = 0; mt < MT; ++mt)
#pragma unroll
                for (int nt = 0; nt < NTW; ++nt)
                    acc[mt][nt] = mfma16<ET>(af[mt][kk], bv[nt][kk], acc[mt][nt]);

        // all our ds_reads must COMPLETE before any wave passes the barrier
        // (next iter's DMA overwrites buf[cur]); MFMA sinking past is harmless.
        asm volatile("s_waitcnt lgkmcnt(0)" ::: "memory");
        __builtin_amdgcn_s_barrier();
        cur ^= 1;
    }

    int f = 0;
    if (MODE == 0) f = flag[0];

    // C/D layout: col = lane&15, row = (lane>>4)*4 + r   [m89/m91]
    const int coln = lane & 15;
    const int rq   = lane >> 4;
#pragma unroll
    for (int mt = 0; mt < MT; ++mt) {
#pragma unroll
        for (int r = 0; r < 4; ++r) {
            const int gm = bm + wm * 64 + mt * 16 + rq * 4 + r;
#pragma unroll
            for (int nt = 0; nt < NTW; ++nt) {
                const int gn = bn + wn * (NTW * 16) + nt * 16 + coln;
                const float c = acc[mt][nt][r];
                if (MODE == 0) {
                    if (gn < N) {
                        const size_t xi = (size_t)gm * N + gn;
                        const float xv = f ? ((const float*)Xin)[xi]
                                           : (float)((const bf16_t*)Xin)[xi];
                        Out[(size_t)gm * ldo + gn] = (ET)(xv - c);
                    }
                } else if (MODE == 1) {
                    const size_t idx = (size_t)gm * ldo + gn;
                    const float uo = U[idx];
                    const float ao = fmaxf(uo - 0.3f, 0.0f);
                    const float un = uo + 0.01f * (c + ao - uo);
                    U[idx] = un;
                    Out[idx] = (ET)fmaxf(un - 0.3f, 0.0f);
                } else if (MODE == 3) {
                    const size_t idx = (size_t)gm * ldo + gn;
                    const float uo = U[idx];
                    const float bb = BF32 ? ((const float*)Xin)[idx]
                                          : (float)((const ET*)Xin)[idx];
                    const float un = uo + 0.01f * (bb - c - uo);
                    U[idx] = un;
                    Out[idx] = (ET)fmaxf(un - 0.3f, 0.0f);
                } else if (MODE == 4) {
                    U[(size_t)gm * ldo + gn] = c;
                } else if (MODE == 5) {
                    Out[(size_t)gm * ldo + gn] = (ET)(gm == gn ? c - 1.0f : c);
                } else {
                    if (gn < N)
                        Out[(size_t)gm * ldo + gn] = (ET)c;
                }
            }
        }
    }
}

// final a: f16 (ws) -> d_out a-region (f32 or bf16 per flag). src in ws, no
// overlap with dst -> single pass.
__global__ void a_out(const f16_t* __restrict__ src, void* __restrict__ dout,
                      const int* __restrict__ flag) {
    long i = (long)blockIdx.x * 256 + threadIdx.x;
    if (i >= 16777216L) return;
    const float v = (float)src[i];
    if (flag[0]) ((float*)dout)[6422528L + i] = v;
    else         ((bf16_t*)dout)[6422528L + i] = (bf16_t)v;
}

// recon: f16 (ws) -> d_out front (f32 or bf16 per flag)
__global__ void recon_out_h(const f16_t* __restrict__ rec, void* __restrict__ dout,
                            const int* __restrict__ flag) {
    long i = (long)blockIdx.x * 256 + threadIdx.x;
    if (i >= 6422528L) return;
    const float v = (float)rec[i];
    if (flag[0]) ((float*)dout)[i] = v;
    else         ((bf16_t*)dout)[i] = (bf16_t)v;
}

// ---- fallback-path epilogue kernels (bf16 residual form) ----
__global__ void a_move(const bf16_t* __restrict__ src, float* __restrict__ dst,
                       long lo, long hi, const int* __restrict__ flag) {
    if (!flag[0]) return;
    long i = lo + (long)blockIdx.x * 256 + threadIdx.x;
    if (i < hi) dst[i] = (float)src[i];
}

__global__ void recon_out(const bf16_t* __restrict__ rec, void* __restrict__ dout,
                          const int* __restrict__ flag) {
    long i = (long)blockIdx.x * 256 + threadIdx.x;
    if (i >= 6422528L) return;
    if (flag[0]) ((float*)dout)[i] = (float)rec[i];
    else         ((bf16_t*)dout)[i] = rec[i];
}

extern "C" void kernel_launch(void* const* d_in, const int* in_sizes, int n_in,
                              void* d_out, int out_size, void* d_ws, size_t ws_size,
                              hipStream_t stream) {
    const void* x = d_in[0];   // [8192, 784]  fp32 or bf16
    const void* w = d_in[1];   // [784, 2048]  fp32 or bf16
    (void)in_sizes; (void)n_in; (void)out_size;

    char* ws = (char*)d_ws;
    const bool tier1 = ws_size >= 179437572UL;   // b in f32
    const bool tier2 = ws_size >= 145883140UL;   // b in f16 (ws>=162.2 proven)

    if (tier1 || tier2) {
        // ---------- f16 G-form path ----------
        float*  u    = (float*)ws;                          // [0, 67.1MB)
        f16_t*  xh   = (f16_t*)ws;                          // aliases u pre-iter
        float*  bF   = (float*)(ws + 67108864);             // tier1: f32 b
        f16_t*  bH   = (f16_t*)(ws + 67108864);             // tier2: f16 b
        const size_t goff = tier1 ? 134217728UL : 100663296UL;
        f16_t*  g    = (f16_t*)(ws + goff);                 // 8,388,608
        f16_t*  wTh  = (f16_t*)(ws + goff + 8388608);       // 3,276,800
        f16_t*  aP0  = (f16_t*)(ws + goff + 11665408);      // 33,554,432
        int*    flag = (int*)(ws + goff + 45219840);
        f16_t*  aP1  = (f16_t*)d_out;                       // 33.5MB d_out scratch
        f16_t*  wBh  = (f16_t*)ws;                          // aliases u post-loop
        f16_t*  rec  = (f16_t*)(ws + 4194304);              // aliases u post-loop

        sniff<<<1, 256, 0, stream>>>((const uint16_t*)w, flag);
        build_wh<<<dim3(4, 2048), 256, 0, stream>>>(w, wTh, flag);
        build_xh<<<dim3(4, 8192), 256, 0, stream>>>(x, xh, flag);

        // b = xh @ w   (xh aliases u -> b-GEMM BEFORE u init)
        if (tier1)
            gemm_nt<4, false, 128, 32, 4, f16_t><<<dim3(64, 16), 256, 0, stream>>>(
                xh, wTh, 2048, 800, 800, 800, nullptr, bF, nullptr, 2048, flag);
        else
            gemm_nt<2, false, 128, 32, 4, f16_t><<<dim3(64, 16), 256, 0, stream>>>(
                xh, wTh, 2048, 800, 800, 800, nullptr, nullptr, bH, 2048, flag);
        // g = w^T w - I (f16; diag subtracted in f32 before rounding)
        gemm_nt<5, false, 128, 32, 4, f16_t><<<dim3(16, 16), 256, 0, stream>>>(
            wTh, wTh, 2048, 800, 800, 800, nullptr, nullptr, g, 2048, flag);

        fill0<<<16384, 256, 0, stream>>>((int4v*)u, 4194304L);   // u = 0
        fill0<<<8192, 256, 0, stream>>>((int4v*)aP1, 2097152L);  // a_0 = 0

        // 99 fused steps: C = a@g; u += 0.01*(b - C - u); a = relu(u-0.3)
        // ping-pong (WAR-safe across bn-blocks): i reads aP[i&1], writes
        // aP[(i+1)&1]; i=1..99 -> final a in aP0 (ws).
        for (int i = 1; i <= 99; ++i) {
            f16_t* rd = (i & 1) ? aP1 : aP0;
            f16_t* wr = (i & 1) ? aP0 : aP1;
            if (tier1)
                gemm_nt<3, false, 128, 32, 4, f16_t, true>
                    <<<dim3(64, 16), 256, 0, stream>>>(
                    rd, g, 2048, 2048, 2048, 2048, bF, u, wr, 2048, flag);
            else
                gemm_nt<3, false, 128, 32, 4, f16_t, false>
                    <<<dim3(64, 16), 256, 0, stream>>>(
                    rd, g, 2048, 2048, 2048, 2048, bH, u, wr, 2048, flag);
        }

        // u dead: build wBh + rec into u's region; recon = a @ w^T
        build_wbh<<<dim3(8, 784), 256, 0, stream>>>(w, wBh, flag);
        gemm_nt<2, true, 128, 32, 8, f16_t><<<dim3(64, 7), 512, 0, stream>>>(
            aP0, wBh, 784, 2048, 2048, 2048, nullptr, nullptr, rec, 784, flag);

        // outputs (aP1 at d_out dead from here; writes ordered after reads)
        a_out<<<65536, 256, 0, stream>>>(aP0, d_out, flag);
        recon_out_h<<<25088, 256, 0, stream>>>(rec, d_out, flag);
        return;
    }

    // ---------- fallback: round-10 residual path (passed, 9.39 ms) ----------
    float*  u    = (float*)ws;                          // 67,108,864 B
    bf16_t* r    = (bf16_t*)(ws + 67108864);            // 13,107,200 B (8192x800)
    bf16_t* wT   = (bf16_t*)(ws + 80216064);            //  3,276,800 B (2048x800)
    bf16_t* wB   = (bf16_t*)(ws + 83492864);            //  3,211,264 B (784x2048)
    int*    flag = (int*)(ws + 86704128);               // total 86.7 MB
    bf16_t* aA   = (bf16_t*)((char*)d_out + 12845056);  // a scratch
    bf16_t* rec  = r;

    sniff<<<1, 256, 0, stream>>>((const uint16_t*)w, flag);
    fill0<<<16384, 256, 0, stream>>>((int4v*)u, 4194304L);   // u = 0
    fill0<<<3200, 256, 0, stream>>>((int4v*)r, 819200L);     // r = 0 (incl. pad)
    fill0<<<8192, 256, 0, stream>>>((int4v*)aA, 2097152L);   // a = 0
    build_w<<<dim3(4, 2048), 256, 0, stream>>>(w, wT, wB, flag);

    for (int i = 0; i < 99; ++i) {
        gemm_nt<0, true, 128, 32, 8><<<dim3(64, 7), 512, 0, stream>>>(
            aA, wB, 784, 2048, 2048, 2048, x, nullptr, r, 800, flag);
        gemm_nt<1, false, 128, 32, 4><<<dim3(64, 16), 256, 0, stream>>>(
            r, wT, 2048, 800, 800, 800, nullptr, u, aA, 2048, flag);
    }

    gemm_nt<2, true, 128, 32, 8><<<dim3(64, 7), 512, 0, stream>>>(
        aA, wB, 784, 2048, 2048, 2048, nullptr, nullptr, rec, 784, flag);

    float* aOutF = (float*)d_out + 6422528;
    a_move<<<45312, 256, 0, stream>>>(aA, aOutF, 5177344L, 16777216L, flag);
    a_move<<<20224, 256, 0, stream>>>(aA, aOutF, 0L, 5177344L, flag);
    recon_out<<<25088, 256, 0, stream>>>(rec, d_out, flag);
}

// Round 11
// 9230.845 us; speedup vs baseline: 1.1048x; 1.1048x over previous
//
#include <hip/hip_runtime.h>
#include <hip/hip_bf16.h>
#include <stdint.h>

// LCA on MI355X, round 16 (= round 15 resubmitted after MI355X container infra
// failure; no kernel change). G-form f16 (PASSED r14 at absmax 0.015625,
// 10.2ms). r14 counter decomposition of MODE 3 (~114us): GEMM phase ~70us
// LDS-bound (8.4MB ds_read/CU @85B/cyc + 14us of 4-way CPR=4 conflicts) +
// ~42us serialized epilogue burst (235MB). Changes vs r14:
//  - MODE 3 geometry: NW=8 (512thr, 2x4 waves, per-wave 64x32) + TBK=64
//    (CPR=8 fold row&7 = the ONLY measured-0-conflict config, r7). Per-CU
//    ds_read bytes 8.4->6.1MB, conflicts ->0. LDS 64KB -> 2 blocks/CU =
//    16 waves/CU (unchanged residency). Absolute k-order unchanged.
//  - MODE 3 epilogue: gather-then-compute (load all 32 b + 32 u into regs,
//    then compute+store) -- batches the burst's loads, hides latency.
// Everything else identical to r14 (tiers, f16 path, prologue, outputs,
// a ping-pong, residual-form fallback).

typedef __bf16 bf16_t;
typedef _Float16 f16_t;
typedef float f32x4 __attribute__((ext_vector_type(4)));
typedef __bf16 bf16x8 __attribute__((ext_vector_type(8)));
typedef _Float16 f16x8 __attribute__((ext_vector_type(8)));
typedef int int4v __attribute__((ext_vector_type(4)));

#define BM 128

template <typename ET>
static __device__ __forceinline__ f32x4 mfma16(int4v a, int4v b, f32x4 c) {
    if constexpr (__is_same(ET, bf16_t))
        return __builtin_amdgcn_mfma_f32_16x16x32_bf16(
            __builtin_bit_cast(bf16x8, a), __builtin_bit_cast(bf16x8, b), c, 0, 0, 0);
    else
        return __builtin_amdgcn_mfma_f32_16x16x32_f16(
            __builtin_bit_cast(f16x8, a), __builtin_bit_cast(f16x8, b), c, 0, 0, 0);
}

// async global->LDS, 16B/lane; LDS dest = wave-uniform base + lane*16.
static __device__ __forceinline__ void gl_lds16(const void* gp, void* lp) {
    auto g1 = (const __attribute__((address_space(1))) uint32_t*)(uintptr_t)gp;
    auto l3 = (__attribute__((address_space(3))) uint32_t*)(uintptr_t)lp;
    __builtin_amdgcn_global_load_lds(g1, l3, 16, 0, 0);
}

template <int N>
static __device__ __forceinline__ void vm_wait() {
    if constexpr (N == 0)      asm volatile("s_waitcnt vmcnt(0)" ::: "memory");
    else if constexpr (N == 2) asm volatile("s_waitcnt vmcnt(2)" ::: "memory");
    else if constexpr (N == 4) asm volatile("s_waitcnt vmcnt(4)" ::: "memory");
    else if constexpr (N == 6) asm volatile("s_waitcnt vmcnt(6)" ::: "memory");
    else if constexpr (N == 8) asm volatile("s_waitcnt vmcnt(8)" ::: "memory");
    else                       static_assert(N == 0, "unsupported vmcnt");
}

// LDS chunk-swizzle fold. CPR=8: row&7 (measured 0-conflict, r7).
// CPR=4: row&3 (fallback/legacy modes only).
template <int CPR>
static __device__ __forceinline__ int foldf(int r) {
    if constexpr (CPR == 8) return r & 7;
    else                    return r & 3;
}

// flag=1 iff inputs are fp32 (sniff even halfwords of w: fp32 mantissa bits
// look like huge-exponent bf16s; real bf16 |w|<=1 has exp field <= 0x7f).
__global__ void sniff(const uint16_t* __restrict__ wh, int* __restrict__ flag) {
    __shared__ int cnt;
    if (threadIdx.x == 0) cnt = 0;
    __syncthreads();
    int c = 0;
    for (int t = threadIdx.x; t < 4096; t += 256) {
        uint16_t h = wh[(size_t)2 * t * 97];
        c += (((h >> 7) & 0xFF) >= 0x82);
    }
    atomicAdd(&cnt, c);
    __syncthreads();
    if (threadIdx.x == 0) flag[0] = (cnt > 256) ? 1 : 0;
}

__global__ void fill0(int4v* __restrict__ p, long n16) {
    long i = (long)blockIdx.x * 256 + threadIdx.x;
    if (i < n16) p[i] = (int4v){0, 0, 0, 0};
}

static __device__ __forceinline__ float ldin(const void* p, size_t i, int f) {
    return f ? ((const float*)p)[i] : (float)((const bf16_t*)p)[i];
}

// ---- bf16 builders (fallback path) ----
__global__ void build_w(const void* __restrict__ w, bf16_t* __restrict__ wT,
                        bf16_t* __restrict__ wB, const int* __restrict__ flag) {
    const int k = blockIdx.x * 256 + threadIdx.x;
    const int j = blockIdx.y;
    if (k >= 800) return;
    bf16_t v = (bf16_t)0.0f;
    if (k < 784) {
        v = (bf16_t)ldin(w, (size_t)k * 2048 + j, flag[0]);
        wB[(size_t)k * 2048 + j] = v;
    }
    wT[(size_t)j * 800 + k] = v;
}

// ---- f16 builders (G path) ----
__global__ void build_wh(const void* __restrict__ w, f16_t* __restrict__ wTh,
                         const int* __restrict__ flag) {
    const int k = blockIdx.x * 256 + threadIdx.x;   // pixel (pad 800)
    const int j = blockIdx.y;                       // latent
    if (k >= 800) return;
    f16_t v = (f16_t)0.0f;
    if (k < 784) v = (f16_t)ldin(w, (size_t)k * 2048 + j, flag[0]);
    wTh[(size_t)j * 800 + k] = v;
}

__global__ void build_wbh(const void* __restrict__ w, f16_t* __restrict__ wBh,
                          const int* __restrict__ flag) {
    const int j = blockIdx.x * 256 + threadIdx.x;   // latent
    const int p = blockIdx.y;                       // pixel
    if (j >= 2048) return;
    wBh[(size_t)p * 2048 + j] = (f16_t)ldin(w, (size_t)p * 2048 + j, flag[0]);
}

__global__ void build_xh(const void* __restrict__ x, f16_t* __restrict__ xh,
                         const int* __restrict__ flag) {
    const int k = blockIdx.x * 256 + threadIdx.x;   // pixel (pad 800)
    const int i = blockIdx.y;
    if (k >= 800) return;
    f16_t v = (f16_t)0.0f;
    if (k < 784) v = (f16_t)ldin(x, (size_t)i * 784 + k, flag[0]);
    xh[(size_t)i * 800 + k] = v;
}

// NT-GEMM  C[i,j] = sum_k A[i,k]*B[j,k].  Tile BM x BNT, K-step TBK, NW waves
// (wave grid 2 x NW/2; per-wave output 64 x BNT/(NW/2)). Element type ET.
// 2-phase double-buffered: stage tile t+1 via global_load_lds while computing
// tile t; counted s_waitcnt vmcnt(L) keeps next tile's loads in flight across
// the barrier. LDS chunk-XOR swizzle (chunk ^= foldf(row), 16B granularity)
// applied on the global source AND the ds_read address (linear LDS dest).
// MODE 0 (R):    r[gm,gn] = x[gm,gn] - C   (gn<N; x dtype per flag) [fallback]
// MODE 1 (STEP): uo=U; ao=relu(uo-.3); un=uo+.01*(C+ao-uo); U=un; a=relu(un-.3)
// MODE 2 (ETOUT):Out[gm,gn] = (ET)C  (gn<N)
// MODE 3 (GSTEP):uo=U; un=uo+0.01*(b - C - uo); U=un; Out=(ET)relu(un-.3)
//                (b at Xin, f32 if BF32 else ET; g has zero diag)
//                gather-then-compute epilogue (batched b/u loads)
// MODE 4 (F32):  U[gm*ldo+gn] = C
// MODE 5 (GRAM): Out[gm,gn] = (ET)(C - (gm==gn))   -- g = w^T w - I
template <int MODE, bool CLAMPN, int BNT, int TBK, int NW,
          typename ET = bf16_t, bool BF32 = true>
__global__ __launch_bounds__(NW * 64, 4) void gemm_nt(
    const ET* __restrict__ A, const ET* __restrict__ B,
    int N, int K, int lda, int ldb,
    const void* __restrict__ Xin, float* __restrict__ U,
    ET* __restrict__ Out, int ldo, const int* __restrict__ flag)
{
    constexpr int THREADS = NW * 64;
    constexpr int NWN = NW / 2;            // wave-grid cols (2 rows of waves)
    constexpr int MT  = 4;                 // 16-row m-tiles per wave (BM/32)
    constexpr int NTW = BNT / (NWN * 16);  // 16-col n-tiles per wave
    constexpr int CPR = TBK / 8;           // 16B chunks per tile row
    constexpr int AL  = BM * CPR / THREADS;    // A staging insts per thread
    constexpr int BL  = BNT * CPR / THREADS;   // B staging insts per thread
    constexpr int L   = AL + BL;           // loads in flight per tile per wave
    constexpr int KH  = TBK / 32;          // k-halves per tile (MFMA K=32)
    static_assert(AL >= 1 && BL >= 1 && NTW >= 1, "geometry");

    __shared__ __align__(16) ET sA[2][BM * TBK];
    __shared__ __align__(16) ET sB[2][BNT * TBK];

    const int tid  = threadIdx.x;
    const int lane = tid & 63;
    const int wave = tid >> 6;
    const int wm   = wave / NWN;
    const int wn   = wave % NWN;
    const int bm   = blockIdx.x * BM;
    const int bn   = blockIdx.y * BNT;

    f32x4 acc[MT][NTW];
#pragma unroll
    for (int i = 0; i < MT; ++i)
#pragma unroll
        for (int j = 0; j < NTW; ++j) acc[i][j] = (f32x4){0.f, 0.f, 0.f, 0.f};

    // staging map: chunk c = l*THREADS+tid -> LDS row c/CPR, LDS chunk c%CPR,
    // LDS offset c*16B (linear). SOURCE chunk = (c%CPR) ^ foldf(row) so that
    // LDS[row][chunk] holds logical chunk (chunk ^ foldf(row)).
    const ET* gA[AL];
    const ET* gB[BL];
#pragma unroll
    for (int l = 0; l < AL; ++l) {
        const int c  = l * THREADS + tid;
        const int rL = c / CPR;
        const int sc = (c & (CPR - 1)) ^ foldf<CPR>(rL);
        gA[l] = A + (size_t)(bm + rL) * lda + sc * 8;
    }
#pragma unroll
    for (int l = 0; l < BL; ++l) {
        const int c  = l * THREADS + tid;
        const int rL = c / CPR;
        const int sc = (c & (CPR - 1)) ^ foldf<CPR>(rL);
        int rb = bn + rL;
        if (CLAMPN) rb = min(rb, N - 1);
        gB[l] = B + (size_t)rb * ldb + sc * 8;
    }

    auto stage = [&](int buf, int k0) {
#pragma unroll
        for (int l = 0; l < AL; ++l)
            gl_lds16(gA[l] + k0, &sA[buf][(size_t)(l * THREADS + tid) * 8]);
#pragma unroll
        for (int l = 0; l < BL; ++l)
            gl_lds16(gB[l] + k0, &sB[buf][(size_t)(l * THREADS + tid) * 8]);
    };

    const int mrow = lane & 15;
    const int q    = lane >> 4;
    // read-side swizzle: fragment rows are (mult of 16) + mrow, and foldf only
    // uses row bits [2:0] -> per-lane constant.
    const int swz = foldf<CPR>(mrow);
    const int qx  = q ^ (swz & 3);          // low 2 chunk bits
    const int ksw = swz >> 2;               // chunk bit 2 (CPR=8 only)

    stage(0, 0);
    int cur = 0;
    for (int k0 = 0; k0 < K; k0 += TBK) {
        if (k0 + TBK < K) {
            stage(cur ^ 1, k0 + TBK);   // next tile's DMA in flight across barrier
            vm_wait<L>();               // wait only for CURRENT tile's L loads
        } else {
            vm_wait<0>();               // epilogue drain
        }
        __builtin_amdgcn_s_barrier();   // all waves' DMA for buf[cur] landed
        asm volatile("" ::: "memory");  // don't hoist ds_reads above barrier

        int4v af[MT][KH], bv[NTW][KH];
        const ET* pa = &sA[cur][(wm * 64 + mrow) * TBK + qx * 8];
        const ET* pb = &sB[cur][(wn * (NTW * 16) + mrow) * TBK + qx * 8];
#pragma unroll
        for (int t = 0; t < MT; ++t)
#pragma unroll
            for (int kk = 0; kk < KH; ++kk)
                af[t][kk] = *(const int4v*)(pa + t * 16 * TBK + (kk ^ ksw) * 32);
#pragma unroll
        for (int t = 0; t < NTW; ++t)
#pragma unroll
            for (int kk = 0; kk < KH; ++kk)
                bv[t][kk] = *(const int4v*)(pb + t * 16 * TBK + (kk ^ ksw) * 32);
#pragma unroll
        for (int kk = 0; kk < KH; ++kk)       // logical k-order unchanged
#pragma unroll
            for (int mt = 0; mt < MT; ++mt)
#pragma unroll
                for (int nt = 0; nt < NTW; ++nt)
                    acc[mt][nt] = mfma16<ET>(af[mt][kk], bv[nt][kk], acc[mt][nt]);

        // all our ds_reads must COMPLETE before any wave passes the barrier
        // (next iter's DMA overwrites buf[cur]); MFMA sinking past is harmless.
        asm volatile("s_waitcnt lgkmcnt(0)" ::: "memory");
        __builtin_amdgcn_s_barrier();
        cur ^= 1;
    }

    int f = 0;
    if (MODE == 0) f = flag[0];

    // C/D layout: col = lane&15, row = (lane>>4)*4 + r   [m89/m91]
    const int coln = lane & 15;
    const int rq   = lane >> 4;

    if constexpr (MODE == 3) {
        // gather-then-compute: batch all b/u loads (compiler interleaves the
        // 2*MT*4*NTW global_loads; latency overlapped), then compute + store.
        float bb[MT][4][NTW], uu[MT][4][NTW];
#pragma unroll
        for (int mt = 0; mt < MT; ++mt)
#pragma unroll
            for (int r = 0; r < 4; ++r) {
                const int gm = bm + wm * 64 + mt * 16 + rq * 4 + r;
#pragma unroll
                for (int nt = 0; nt < NTW; ++nt) {
                    const int gn = bn + wn * (NTW * 16) + nt * 16 + coln;
                    const size_t idx = (size_t)gm * ldo + gn;
                    bb[mt][r][nt] = BF32 ? ((const float*)Xin)[idx]
                                         : (float)((const ET*)Xin)[idx];
                    uu[mt][r][nt] = U[idx];
                }
            }
#pragma unroll
        for (int mt = 0; mt < MT; ++mt)
#pragma unroll
            for (int r = 0; r < 4; ++r) {
                const int gm = bm + wm * 64 + mt * 16 + rq * 4 + r;
#pragma unroll
                for (int nt = 0; nt < NTW; ++nt) {
                    const int gn = bn + wn * (NTW * 16) + nt * 16 + coln;
                    const size_t idx = (size_t)gm * ldo + gn;
                    const float uo = uu[mt][r][nt];
                    const float un = uo + 0.01f * (bb[mt][r][nt] - acc[mt][nt][r] - uo);
                    U[idx] = un;
                    Out[idx] = (ET)fmaxf(un - 0.3f, 0.0f);
                }
            }
        return;
    }

#pragma unroll
    for (int mt = 0; mt < MT; ++mt) {
#pragma unroll
        for (int r = 0; r < 4; ++r) {
            const int gm = bm + wm * 64 + mt * 16 + rq * 4 + r;
#pragma unroll
            for (int nt = 0; nt < NTW; ++nt) {
                const int gn = bn + wn * (NTW * 16) + nt * 16 + coln;
                const float c = acc[mt][nt][r];
                if (MODE == 0) {
                    if (gn < N) {
                        const size_t xi = (size_t)gm * N + gn;
                        const float xv = f ? ((const float*)Xin)[xi]
                                           : (float)((const bf16_t*)Xin)[xi];
                        Out[(size_t)gm * ldo + gn] = (ET)(xv - c);
                    }
                } else if (MODE == 1) {
                    const size_t idx = (size_t)gm * ldo + gn;
                    const float uo = U[idx];
                    const float ao = fmaxf(uo - 0.3f, 0.0f);
                    const float un = uo + 0.01f * (c + ao - uo);
                    U[idx] = un;
                    Out[idx] = (ET)fmaxf(un - 0.3f, 0.0f);
                } else if (MODE == 4) {
                    U[(size_t)gm * ldo + gn] = c;
                } else if (MODE == 5) {
                    Out[(size_t)gm * ldo + gn] = (ET)(gm == gn ? c - 1.0f : c);
                } else {
                    if (gn < N)
                        Out[(size_t)gm * ldo + gn] = (ET)c;
                }
            }
        }
    }
}

// final a: f16 (ws) -> d_out a-region (f32 or bf16 per flag). src in ws, no
// overlap with dst -> single pass.
__global__ void a_out(const f16_t* __restrict__ src, void* __restrict__ dout,
                      const int* __restrict__ flag) {
    long i = (long)blockIdx.x * 256 + threadIdx.x;
    if (i >= 16777216L) return;
    const float v = (float)src[i];
    if (flag[0]) ((float*)dout)[6422528L + i] = v;
    else         ((bf16_t*)dout)[6422528L + i] = (bf16_t)v;
}

// recon: f16 (ws) -> d_out front (f32 or bf16 per flag)
__global__ void recon_out_h(const f16_t* __restrict__ rec, void* __restrict__ dout,
                            const int* __restrict__ flag) {
    long i = (long)blockIdx.x * 256 + threadIdx.x;
    if (i >= 6422528L) return;
    const float v = (float)rec[i];
    if (flag[0]) ((float*)dout)[i] = v;
    else         ((bf16_t*)dout)[i] = (bf16_t)v;
}

// ---- fallback-path epilogue kernels (bf16 residual form) ----
__global__ void a_move(const bf16_t* __restrict__ src, float* __restrict__ dst,
                       long lo, long hi, const int* __restrict__ flag) {
    if (!flag[0]) return;
    long i = lo + (long)blockIdx.x * 256 + threadIdx.x;
    if (i < hi) dst[i] = (float)src[i];
}

__global__ void recon_out(const bf16_t* __restrict__ rec, void* __restrict__ dout,
                          const int* __restrict__ flag) {
    long i = (long)blockIdx.x * 256 + threadIdx.x;
    if (i >= 6422528L) return;
    if (flag[0]) ((float*)dout)[i] = (float)rec[i];
    else         ((bf16_t*)dout)[i] = rec[i];
}

extern "C" void kernel_launch(void* const* d_in, const int* in_sizes, int n_in,
                              void* d_out, int out_size, void* d_ws, size_t ws_size,
                              hipStream_t stream) {
    const void* x = d_in[0];   // [8192, 784]  fp32 or bf16
    const void* w = d_in[1];   // [784, 2048]  fp32 or bf16
    (void)in_sizes; (void)n_in; (void)out_size;

    char* ws = (char*)d_ws;
    const bool tier1 = ws_size >= 179437572UL;   // b in f32
    const bool tier2 = ws_size >= 145883140UL;   // b in f16 (ws>=162.2 proven)

    if (tier1 || tier2) {
        // ---------- f16 G-form path ----------
        float*  u    = (float*)ws;                          // [0, 67.1MB)
        f16_t*  xh   = (f16_t*)ws;                          // aliases u pre-iter
        float*  bF   = (float*)(ws + 67108864);             // tier1: f32 b
        f16_t*  bH   = (f16_t*)(ws + 67108864);             // tier2: f16 b
        const size_t goff = tier1 ? 134217728UL : 100663296UL;
        f16_t*  g    = (f16_t*)(ws + goff);                 // 8,388,608
        f16_t*  wTh  = (f16_t*)(ws + goff + 8388608);       // 3,276,800
        f16_t*  aP0  = (f16_t*)(ws + goff + 11665408);      // 33,554,432
        int*    flag = (int*)(ws + goff + 45219840);
        f16_t*  aP1  = (f16_t*)d_out;                       // 33.5MB d_out scratch
        f16_t*  wBh  = (f16_t*)ws;                          // aliases u post-loop
        f16_t*  rec  = (f16_t*)(ws + 4194304);              // aliases u post-loop

        sniff<<<1, 256, 0, stream>>>((const uint16_t*)w, flag);
        build_wh<<<dim3(4, 2048), 256, 0, stream>>>(w, wTh, flag);
        build_xh<<<dim3(4, 8192), 256, 0, stream>>>(x, xh, flag);

        // b = xh @ w   (xh aliases u -> b-GEMM BEFORE u init)
        if (tier1)
            gemm_nt<4, false, 128, 32, 4, f16_t><<<dim3(64, 16), 256, 0, stream>>>(
                xh, wTh, 2048, 800, 800, 800, nullptr, bF, nullptr, 2048, flag);
        else
            gemm_nt<2, false, 128, 32, 4, f16_t><<<dim3(64, 16), 256, 0, stream>>>(
                xh, wTh, 2048, 800, 800, 800, nullptr, nullptr, bH, 2048, flag);
        // g = w^T w - I (f16; diag subtracted in f32 before rounding)
        gemm_nt<5, false, 128, 32, 4, f16_t><<<dim3(16, 16), 256, 0, stream>>>(
            wTh, wTh, 2048, 800, 800, 800, nullptr, nullptr, g, 2048, flag);

        fill0<<<16384, 256, 0, stream>>>((int4v*)u, 4194304L);   // u = 0
        fill0<<<8192, 256, 0, stream>>>((int4v*)aP1, 2097152L);  // a_0 = 0

        // 99 fused steps: C = a@g; u += 0.01*(b - C - u); a = relu(u-0.3)
        // NW=8/TBK=64 (0-conflict CPR=8, per-wave 64x32, 2 blocks/CU);
        // ping-pong (WAR-safe across bn-blocks): i reads aP[i&1], writes
        // aP[(i+1)&1]; i=1..99 -> final a in aP0 (ws).
        for (int i = 1; i <= 99; ++i) {
            f16_t* rd = (i & 1) ? aP1 : aP0;
            f16_t* wr = (i & 1) ? aP0 : aP1;
            if (tier1)
                gemm_nt<3, false, 128, 64, 8, f16_t, true>
                    <<<dim3(64, 16), 512, 0, stream>>>(
                    rd, g, 2048, 2048, 2048, 2048, bF, u, wr, 2048, flag);
            else
                gemm_nt<3, false, 128, 64, 8, f16_t, false>
                    <<<dim3(64, 16), 512, 0, stream>>>(
                    rd, g, 2048, 2048, 2048, 2048, bH, u, wr, 2048, flag);
        }

        // u dead: build wBh + rec into u's region; recon = a @ w^T
        build_wbh<<<dim3(8, 784), 256, 0, stream>>>(w, wBh, flag);
        gemm_nt<2, true, 128, 32, 8, f16_t><<<dim3(64, 7), 512, 0, stream>>>(
            aP0, wBh, 784, 2048, 2048, 2048, nullptr, nullptr, rec, 784, flag);

        // outputs (aP1 at d_out dead from here; writes ordered after reads)
        a_out<<<65536, 256, 0, stream>>>(aP0, d_out, flag);
        recon_out_h<<<25088, 256, 0, stream>>>(rec, d_out, flag);
        return;
    }

    // ---------- fallback: round-10 residual path (passed, 9.39 ms) ----------
    float*  u    = (float*)ws;                          // 67,108,864 B
    bf16_t* r    = (bf16_t*)(ws + 67108864);            // 13,107,200 B (8192x800)
    bf16_t* wT   = (bf16_t*)(ws + 80216064);            //  3,276,800 B (2048x800)
    bf16_t* wB   = (bf16_t*)(ws + 83492864);            //  3,211,264 B (784x2048)
    int*    flag = (int*)(ws + 86704128);               // total 86.7 MB
    bf16_t* aA   = (bf16_t*)((char*)d_out + 12845056);  // a scratch
    bf16_t* rec  = r;

    sniff<<<1, 256, 0, stream>>>((const uint16_t*)w, flag);
    fill0<<<16384, 256, 0, stream>>>((int4v*)u, 4194304L);   // u = 0
    fill0<<<3200, 256, 0, stream>>>((int4v*)r, 819200L);     // r = 0 (incl. pad)
    fill0<<<8192, 256, 0, stream>>>((int4v*)aA, 2097152L);   // a = 0
    build_w<<<dim3(4, 2048), 256, 0, stream>>>(w, wT, wB, flag);

    for (int i = 0; i < 99; ++i) {
        gemm_nt<0, true, 128, 32, 8><<<dim3(64, 7), 512, 0, stream>>>(
            aA, wB, 784, 2048, 2048, 2048, x, nullptr, r, 800, flag);
        gemm_nt<1, false, 128, 32, 4><<<dim3(64, 16), 256, 0, stream>>>(
            r, wT, 2048, 800, 800, 800, nullptr, u, aA, 2048, flag);
    }

    gemm_nt<2, true, 128, 32, 8><<<dim3(64, 7), 512, 0, stream>>>(
        aA, wB, 784, 2048, 2048, 2048, nullptr, nullptr, rec, 784, flag);

    float* aOutF = (float*)d_out + 6422528;
    a_move<<<45312, 256, 0, stream>>>(aA, aOutF, 5177344L, 16777216L, flag);
    a_move<<<20224, 256, 0, stream>>>(aA, aOutF, 0L, 5177344L, flag);
    recon_out<<<25088, 256, 0, stream>>>(rec, d_out, flag);
}

// Round 12
// 8100.661 us; speedup vs baseline: 1.2590x; 1.1395x over previous
//
#include <hip/hip_runtime.h>
#include <hip/hip_bf16.h>
#include <stdint.h>

// LCA on MI355X, round 17. G-form f16 (PASSED r16: 9.23ms, absmax 0.015625).
// r16 counter decomposition of MODE 3 (~106us): the 2x4 wave grid duplicates
// A-reads 4x -> 12MB/CU ds_read ~58us + epilogue 268MB ~42us. Changes:
//  - MODE 3 geometry: NW=4 SQUARE 2x2 grid (64x64/wave), TBK=64 (0-conflict
//    CPR=8 row&7). Per-CU ds_read 12->8MB (A/B dup both 2x = minimum).
//    k-order unchanged -> GEMM numerics identical. Gather epilogue needs
//    ~200 VGPR -> new WEU launch_bounds param = 2 for this instantiation
//    (256thr, 2 waves/EU -> 256 VGPR budget; LDS 64KB caps 2 blocks/CU).
//  - b always f16 (single tier; was f32 in tier1): epilogue 268->234MB.
//    delta-b<=0.004 enters u as 0.63*db ~ 0.0025 -- negligible vs headroom.
// ws need 145.9MB (proven available); fallback: residual path (9.39ms).

typedef __bf16 bf16_t;
typedef _Float16 f16_t;
typedef float f32x4 __attribute__((ext_vector_type(4)));
typedef __bf16 bf16x8 __attribute__((ext_vector_type(8)));
typedef _Float16 f16x8 __attribute__((ext_vector_type(8)));
typedef int int4v __attribute__((ext_vector_type(4)));

#define BM 128

template <typename ET>
static __device__ __forceinline__ f32x4 mfma16(int4v a, int4v b, f32x4 c) {
    if constexpr (__is_same(ET, bf16_t))
        return __builtin_amdgcn_mfma_f32_16x16x32_bf16(
            __builtin_bit_cast(bf16x8, a), __builtin_bit_cast(bf16x8, b), c, 0, 0, 0);
    else
        return __builtin_amdgcn_mfma_f32_16x16x32_f16(
            __builtin_bit_cast(f16x8, a), __builtin_bit_cast(f16x8, b), c, 0, 0, 0);
}

// async global->LDS, 16B/lane; LDS dest = wave-uniform base + lane*16.
static __device__ __forceinline__ void gl_lds16(const void* gp, void* lp) {
    auto g1 = (const __attribute__((address_space(1))) uint32_t*)(uintptr_t)gp;
    auto l3 = (__attribute__((address_space(3))) uint32_t*)(uintptr_t)lp;
    __builtin_amdgcn_global_load_lds(g1, l3, 16, 0, 0);
}

template <int N>
static __device__ __forceinline__ void vm_wait() {
    if constexpr (N == 0)      asm volatile("s_waitcnt vmcnt(0)" ::: "memory");
    else if constexpr (N == 2) asm volatile("s_waitcnt vmcnt(2)" ::: "memory");
    else if constexpr (N == 4) asm volatile("s_waitcnt vmcnt(4)" ::: "memory");
    else if constexpr (N == 6) asm volatile("s_waitcnt vmcnt(6)" ::: "memory");
    else if constexpr (N == 8) asm volatile("s_waitcnt vmcnt(8)" ::: "memory");
    else                       static_assert(N == 0, "unsupported vmcnt");
}

// LDS chunk-swizzle fold. CPR=8: row&7 (measured 0-conflict, r7).
// CPR=4: row&3 (fallback/legacy modes only).
template <int CPR>
static __device__ __forceinline__ int foldf(int r) {
    if constexpr (CPR == 8) return r & 7;
    else                    return r & 3;
}

// flag=1 iff inputs are fp32 (sniff even halfwords of w: fp32 mantissa bits
// look like huge-exponent bf16s; real bf16 |w|<=1 has exp field <= 0x7f).
__global__ void sniff(const uint16_t* __restrict__ wh, int* __restrict__ flag) {
    __shared__ int cnt;
    if (threadIdx.x == 0) cnt = 0;
    __syncthreads();
    int c = 0;
    for (int t = threadIdx.x; t < 4096; t += 256) {
        uint16_t h = wh[(size_t)2 * t * 97];
        c += (((h >> 7) & 0xFF) >= 0x82);
    }
    atomicAdd(&cnt, c);
    __syncthreads();
    if (threadIdx.x == 0) flag[0] = (cnt > 256) ? 1 : 0;
}

__global__ void fill0(int4v* __restrict__ p, long n16) {
    long i = (long)blockIdx.x * 256 + threadIdx.x;
    if (i < n16) p[i] = (int4v){0, 0, 0, 0};
}

static __device__ __forceinline__ float ldin(const void* p, size_t i, int f) {
    return f ? ((const float*)p)[i] : (float)((const bf16_t*)p)[i];
}

// ---- bf16 builders (fallback path) ----
__global__ void build_w(const void* __restrict__ w, bf16_t* __restrict__ wT,
                        bf16_t* __restrict__ wB, const int* __restrict__ flag) {
    const int k = blockIdx.x * 256 + threadIdx.x;
    const int j = blockIdx.y;
    if (k >= 800) return;
    bf16_t v = (bf16_t)0.0f;
    if (k < 784) {
        v = (bf16_t)ldin(w, (size_t)k * 2048 + j, flag[0]);
        wB[(size_t)k * 2048 + j] = v;
    }
    wT[(size_t)j * 800 + k] = v;
}

// ---- f16 builders (G path) ----
__global__ void build_wh(const void* __restrict__ w, f16_t* __restrict__ wTh,
                         const int* __restrict__ flag) {
    const int k = blockIdx.x * 256 + threadIdx.x;   // pixel (pad 800)
    const int j = blockIdx.y;                       // latent
    if (k >= 800) return;
    f16_t v = (f16_t)0.0f;
    if (k < 784) v = (f16_t)ldin(w, (size_t)k * 2048 + j, flag[0]);
    wTh[(size_t)j * 800 + k] = v;
}

__global__ void build_wbh(const void* __restrict__ w, f16_t* __restrict__ wBh,
                          const int* __restrict__ flag) {
    const int j = blockIdx.x * 256 + threadIdx.x;   // latent
    const int p = blockIdx.y;                       // pixel
    if (j >= 2048) return;
    wBh[(size_t)p * 2048 + j] = (f16_t)ldin(w, (size_t)p * 2048 + j, flag[0]);
}

__global__ void build_xh(const void* __restrict__ x, f16_t* __restrict__ xh,
                         const int* __restrict__ flag) {
    const int k = blockIdx.x * 256 + threadIdx.x;   // pixel (pad 800)
    const int i = blockIdx.y;
    if (k >= 800) return;
    f16_t v = (f16_t)0.0f;
    if (k < 784) v = (f16_t)ldin(x, (size_t)i * 784 + k, flag[0]);
    xh[(size_t)i * 800 + k] = v;
}

// NT-GEMM  C[i,j] = sum_k A[i,k]*B[j,k].  Tile BM x BNT, K-step TBK, NW waves
// (wave grid 2 x NW/2; per-wave output 64 x BNT/(NW/2)). Element type ET.
// WEU = launch_bounds min-waves-per-EU (2 -> 256 VGPR budget, 4 -> 128).
// 2-phase double-buffered: stage tile t+1 via global_load_lds while computing
// tile t; counted s_waitcnt vmcnt(L) keeps next tile's loads in flight across
// the barrier. LDS chunk-XOR swizzle (chunk ^= foldf(row), 16B granularity)
// applied on the global source AND the ds_read address (linear LDS dest).
// MODE 0 (R):    r[gm,gn] = x[gm,gn] - C   (gn<N; x dtype per flag) [fallback]
// MODE 1 (STEP): uo=U; ao=relu(uo-.3); un=uo+.01*(C+ao-uo); U=un; a=relu(un-.3)
// MODE 2 (ETOUT):Out[gm,gn] = (ET)C  (gn<N)
// MODE 3 (GSTEP):uo=U; un=uo+0.01*(b - C - uo); U=un; Out=(ET)relu(un-.3)
//                (b at Xin, f32 if BF32 else ET; g has zero diag)
//                gather-then-compute epilogue (batched b/u loads)
// MODE 4 (F32):  U[gm*ldo+gn] = C
// MODE 5 (GRAM): Out[gm,gn] = (ET)(C - (gm==gn))   -- g = w^T w - I
template <int MODE, bool CLAMPN, int BNT, int TBK, int NW,
          typename ET = bf16_t, bool BF32 = true, int WEU = 4>
__global__ __launch_bounds__(NW * 64, WEU) void gemm_nt(
    const ET* __restrict__ A, const ET* __restrict__ B,
    int N, int K, int lda, int ldb,
    const void* __restrict__ Xin, float* __restrict__ U,
    ET* __restrict__ Out, int ldo, const int* __restrict__ flag)
{
    constexpr int THREADS = NW * 64;
    constexpr int NWN = NW / 2;            // wave-grid cols (2 rows of waves)
    constexpr int MT  = 4;                 // 16-row m-tiles per wave (BM/32)
    constexpr int NTW = BNT / (NWN * 16);  // 16-col n-tiles per wave
    constexpr int CPR = TBK / 8;           // 16B chunks per tile row
    constexpr int AL  = BM * CPR / THREADS;    // A staging insts per thread
    constexpr int BL  = BNT * CPR / THREADS;   // B staging insts per thread
    constexpr int L   = AL + BL;           // loads in flight per tile per wave
    constexpr int KH  = TBK / 32;          // k-halves per tile (MFMA K=32)
    static_assert(AL >= 1 && BL >= 1 && NTW >= 1, "geometry");

    __shared__ __align__(16) ET sA[2][BM * TBK];
    __shared__ __align__(16) ET sB[2][BNT * TBK];

    const int tid  = threadIdx.x;
    const int lane = tid & 63;
    const int wave = tid >> 6;
    const int wm   = wave / NWN;
    const int wn   = wave % NWN;
    const int bm   = blockIdx.x * BM;
    const int bn   = blockIdx.y * BNT;

    f32x4 acc[MT][NTW];
#pragma unroll
    for (int i = 0; i < MT; ++i)
#pragma unroll
        for (int j = 0; j < NTW; ++j) acc[i][j] = (f32x4){0.f, 0.f, 0.f, 0.f};

    // staging map: chunk c = l*THREADS+tid -> LDS row c/CPR, LDS chunk c%CPR,
    // LDS offset c*16B (linear). SOURCE chunk = (c%CPR) ^ foldf(row) so that
    // LDS[row][chunk] holds logical chunk (chunk ^ foldf(row)).
    const ET* gA[AL];
    const ET* gB[BL];
#pragma unroll
    for (int l = 0; l < AL; ++l) {
        const int c  = l * THREADS + tid;
        const int rL = c / CPR;
        const int sc = (c & (CPR - 1)) ^ foldf<CPR>(rL);
        gA[l] = A + (size_t)(bm + rL) * lda + sc * 8;
    }
#pragma unroll
    for (int l = 0; l < BL; ++l) {
        const int c  = l * THREADS + tid;
        const int rL = c / CPR;
        const int sc = (c & (CPR - 1)) ^ foldf<CPR>(rL);
        int rb = bn + rL;
        if (CLAMPN) rb = min(rb, N - 1);
        gB[l] = B + (size_t)rb * ldb + sc * 8;
    }

    auto stage = [&](int buf, int k0) {
#pragma unroll
        for (int l = 0; l < AL; ++l)
            gl_lds16(gA[l] + k0, &sA[buf][(size_t)(l * THREADS + tid) * 8]);
#pragma unroll
        for (int l = 0; l < BL; ++l)
            gl_lds16(gB[l] + k0, &sB[buf][(size_t)(l * THREADS + tid) * 8]);
    };

    const int mrow = lane & 15;
    const int q    = lane >> 4;
    // read-side swizzle: fragment rows are (mult of 16) + mrow, and foldf only
    // uses row bits [2:0] -> per-lane constant.
    const int swz = foldf<CPR>(mrow);
    const int qx  = q ^ (swz & 3);          // low 2 chunk bits
    const int ksw = swz >> 2;               // chunk bit 2 (CPR=8 only)

    stage(0, 0);
    int cur = 0;
    for (int k0 = 0; k0 < K; k0 += TBK) {
        if (k0 + TBK < K) {
            stage(cur ^ 1, k0 + TBK);   // next tile's DMA in flight across barrier
            vm_wait<L>();               // wait only for CURRENT tile's L loads
        } else {
            vm_wait<0>();               // epilogue drain
        }
        __builtin_amdgcn_s_barrier();   // all waves' DMA for buf[cur] landed
        asm volatile("" ::: "memory");  // don't hoist ds_reads above barrier

        int4v af[MT][KH], bv[NTW][KH];
        const ET* pa = &sA[cur][(wm * 64 + mrow) * TBK + qx * 8];
        const ET* pb = &sB[cur][(wn * (NTW * 16) + mrow) * TBK + qx * 8];
#pragma unroll
        for (int t = 0; t < MT; ++t)
#pragma unroll
            for (int kk = 0; kk < KH; ++kk)
                af[t][kk] = *(const int4v*)(pa + t * 16 * TBK + (kk ^ ksw) * 32);
#pragma unroll
        for (int t = 0; t < NTW; ++t)
#pragma unroll
            for (int kk = 0; kk < KH; ++kk)
                bv[t][kk] = *(const int4v*)(pb + t * 16 * TBK + (kk ^ ksw) * 32);
#pragma unroll
        for (int kk = 0; kk < KH; ++kk)       // logical k-order unchanged
#pragma unroll
            for (int mt = 0; mt < MT; ++mt)
#pragma unroll
                for (int nt = 0; nt < NTW; ++nt)
                    acc[mt][nt] = mfma16<ET>(af[mt][kk], bv[nt][kk], acc[mt][nt]);

        // all our ds_reads must COMPLETE before any wave passes the barrier
        // (next iter's DMA overwrites buf[cur]); MFMA sinking past is harmless.
        asm volatile("s_waitcnt lgkmcnt(0)" ::: "memory");
        __builtin_amdgcn_s_barrier();
        cur ^= 1;
    }

    int f = 0;
    if (MODE == 0) f = flag[0];

    // C/D layout: col = lane&15, row = (lane>>4)*4 + r   [m89/m91]
    const int coln = lane & 15;
    const int rq   = lane >> 4;

    if constexpr (MODE == 3) {
        // gather-then-compute: batch all b/u loads (compiler interleaves the
        // 2*MT*4*NTW global_loads; latency overlapped), then compute + store.
        float bb[MT][4][NTW], uu[MT][4][NTW];
#pragma unroll
        for (int mt = 0; mt < MT; ++mt)
#pragma unroll
            for (int r = 0; r < 4; ++r) {
                const int gm = bm + wm * 64 + mt * 16 + rq * 4 + r;
#pragma unroll
                for (int nt = 0; nt < NTW; ++nt) {
                    const int gn = bn + wn * (NTW * 16) + nt * 16 + coln;
                    const size_t idx = (size_t)gm * ldo + gn;
                    bb[mt][r][nt] = BF32 ? ((const float*)Xin)[idx]
                                         : (float)((const ET*)Xin)[idx];
                    uu[mt][r][nt] = U[idx];
                }
            }
#pragma unroll
        for (int mt = 0; mt < MT; ++mt)
#pragma unroll
            for (int r = 0; r < 4; ++r) {
                const int gm = bm + wm * 64 + mt * 16 + rq * 4 + r;
#pragma unroll
                for (int nt = 0; nt < NTW; ++nt) {
                    const int gn = bn + wn * (NTW * 16) + nt * 16 + coln;
                    const size_t idx = (size_t)gm * ldo + gn;
                    const float uo = uu[mt][r][nt];
                    const float un = uo + 0.01f * (bb[mt][r][nt] - acc[mt][nt][r] - uo);
                    U[idx] = un;
                    Out[idx] = (ET)fmaxf(un - 0.3f, 0.0f);
                }
            }
        return;
    }

#pragma unroll
    for (int mt = 0; mt < MT; ++mt) {
#pragma unroll
        for (int r = 0; r < 4; ++r) {
            const int gm = bm + wm * 64 + mt * 16 + rq * 4 + r;
#pragma unroll
            for (int nt = 0; nt < NTW; ++nt) {
                const int gn = bn + wn * (NTW * 16) + nt * 16 + coln;
                const float c = acc[mt][nt][r];
                if (MODE == 0) {
                    if (gn < N) {
                        const size_t xi = (size_t)gm * N + gn;
                        const float xv = f ? ((const float*)Xin)[xi]
                                           : (float)((const bf16_t*)Xin)[xi];
                        Out[(size_t)gm * ldo + gn] = (ET)(xv - c);
                    }
                } else if (MODE == 1) {
                    const size_t idx = (size_t)gm * ldo + gn;
                    const float uo = U[idx];
                    const float ao = fmaxf(uo - 0.3f, 0.0f);
                    const float un = uo + 0.01f * (c + ao - uo);
                    U[idx] = un;
                    Out[idx] = (ET)fmaxf(un - 0.3f, 0.0f);
                } else if (MODE == 4) {
                    U[(size_t)gm * ldo + gn] = c;
                } else if (MODE == 5) {
                    Out[(size_t)gm * ldo + gn] = (ET)(gm == gn ? c - 1.0f : c);
                } else {
                    if (gn < N)
                        Out[(size_t)gm * ldo + gn] = (ET)c;
                }
            }
        }
    }
}

// final a: f16 (ws) -> d_out a-region (f32 or bf16 per flag). src in ws, no
// overlap with dst -> single pass.
__global__ void a_out(const f16_t* __restrict__ src, void* __restrict__ dout,
                      const int* __restrict__ flag) {
    long i = (long)blockIdx.x * 256 + threadIdx.x;
    if (i >= 16777216L) return;
    const float v = (float)src[i];
    if (flag[0]) ((float*)dout)[6422528L + i] = v;
    else         ((bf16_t*)dout)[6422528L + i] = (bf16_t)v;
}

// recon: f16 (ws) -> d_out front (f32 or bf16 per flag)
__global__ void recon_out_h(const f16_t* __restrict__ rec, void* __restrict__ dout,
                            const int* __restrict__ flag) {
    long i = (long)blockIdx.x * 256 + threadIdx.x;
    if (i >= 6422528L) return;
    const float v = (float)rec[i];
    if (flag[0]) ((float*)dout)[i] = v;
    else         ((bf16_t*)dout)[i] = (bf16_t)v;
}

// ---- fallback-path epilogue kernels (bf16 residual form) ----
__global__ void a_move(const bf16_t* __restrict__ src, float* __restrict__ dst,
                       long lo, long hi, const int* __restrict__ flag) {
    if (!flag[0]) return;
    long i = lo + (long)blockIdx.x * 256 + threadIdx.x;
    if (i < hi) dst[i] = (float)src[i];
}

__global__ void recon_out(const bf16_t* __restrict__ rec, void* __restrict__ dout,
                          const int* __restrict__ flag) {
    long i = (long)blockIdx.x * 256 + threadIdx.x;
    if (i >= 6422528L) return;
    if (flag[0]) ((float*)dout)[i] = (float)rec[i];
    else         ((bf16_t*)dout)[i] = rec[i];
}

extern "C" void kernel_launch(void* const* d_in, const int* in_sizes, int n_in,
                              void* d_out, int out_size, void* d_ws, size_t ws_size,
                              hipStream_t stream) {
    const void* x = d_in[0];   // [8192, 784]  fp32 or bf16
    const void* w = d_in[1];   // [784, 2048]  fp32 or bf16
    (void)in_sizes; (void)n_in; (void)out_size;

    char* ws = (char*)d_ws;

    if (ws_size >= 145883140UL) {
        // ---------- f16 G-form path (single tier, b in f16) ----------
        float*  u    = (float*)ws;                          // [0, 67.1MB)
        f16_t*  xh   = (f16_t*)ws;                          // aliases u pre-iter
        f16_t*  bH   = (f16_t*)(ws + 67108864);             // 33,554,432
        f16_t*  g    = (f16_t*)(ws + 100663296);            //  8,388,608
        f16_t*  wTh  = (f16_t*)(ws + 109051904);            //  3,276,800
        f16_t*  aP0  = (f16_t*)(ws + 112328704);            // 33,554,432
        int*    flag = (int*)(ws + 145883136);
        f16_t*  aP1  = (f16_t*)d_out;                       // 33.5MB d_out scratch
        f16_t*  wBh  = (f16_t*)ws;                          // aliases u post-loop
        f16_t*  rec  = (f16_t*)(ws + 4194304);              // aliases u post-loop

        sniff<<<1, 256, 0, stream>>>((const uint16_t*)w, flag);
        build_wh<<<dim3(4, 2048), 256, 0, stream>>>(w, wTh, flag);
        build_xh<<<dim3(4, 8192), 256, 0, stream>>>(x, xh, flag);

        // b = xh @ w (f16; xh aliases u -> b-GEMM BEFORE u init)
        gemm_nt<2, false, 128, 32, 4, f16_t><<<dim3(64, 16), 256, 0, stream>>>(
            xh, wTh, 2048, 800, 800, 800, nullptr, nullptr, bH, 2048, flag);
        // g = w^T w - I (f16; diag subtracted in f32 before rounding)
        gemm_nt<5, false, 128, 32, 4, f16_t><<<dim3(16, 16), 256, 0, stream>>>(
            wTh, wTh, 2048, 800, 800, 800, nullptr, nullptr, g, 2048, flag);

        fill0<<<16384, 256, 0, stream>>>((int4v*)u, 4194304L);   // u = 0
        fill0<<<8192, 256, 0, stream>>>((int4v*)aP1, 2097152L);  // a_0 = 0

        // 99 fused steps: C = a@g; u += 0.01*(b - C - u); a = relu(u-0.3)
        // NW=4 2x2 grid (64x64/wave, minimal LDS dup), TBK=64 (0-conflict),
        // WEU=2 (256 VGPR budget for gather epilogue; LDS caps 2 blocks/CU).
        // ping-pong (WAR-safe across bn-blocks): i reads aP[i&1], writes
        // aP[(i+1)&1]; i=1..99 -> final a in aP0 (ws).
        for (int i = 1; i <= 99; ++i) {
            f16_t* rd = (i & 1) ? aP1 : aP0;
            f16_t* wr = (i & 1) ? aP0 : aP1;
            gemm_nt<3, false, 128, 64, 4, f16_t, false, 2>
                <<<dim3(64, 16), 256, 0, stream>>>(
                rd, g, 2048, 2048, 2048, 2048, bH, u, wr, 2048, flag);
        }

        // u dead: build wBh + rec into u's region; recon = a @ w^T
        build_wbh<<<dim3(8, 784), 256, 0, stream>>>(w, wBh, flag);
        gemm_nt<2, true, 128, 32, 8, f16_t><<<dim3(64, 7), 512, 0, stream>>>(
            aP0, wBh, 784, 2048, 2048, 2048, nullptr, nullptr, rec, 784, flag);

        // outputs (aP1 at d_out dead from here; writes ordered after reads)
        a_out<<<65536, 256, 0, stream>>>(aP0, d_out, flag);
        recon_out_h<<<25088, 256, 0, stream>>>(rec, d_out, flag);
        return;
    }

    // ---------- fallback: round-10 residual path (passed, 9.39 ms) ----------
    float*  u    = (float*)ws;                          // 67,108,864 B
    bf16_t* r    = (bf16_t*)(ws + 67108864);            // 13,107,200 B (8192x800)
    bf16_t* wT   = (bf16_t*)(ws + 80216064);            //  3,276,800 B (2048x800)
    bf16_t* wB   = (bf16_t*)(ws + 83492864);            //  3,211,264 B (784x2048)
    int*    flag = (int*)(ws + 86704128);               // total 86.7 MB
    bf16_t* aA   = (bf16_t*)((char*)d_out + 12845056);  // a scratch
    bf16_t* rec  = r;

    sniff<<<1, 256, 0, stream>>>((const uint16_t*)w, flag);
    fill0<<<16384, 256, 0, stream>>>((int4v*)u, 4194304L);   // u = 0
    fill0<<<3200, 256, 0, stream>>>((int4v*)r, 819200L);     // r = 0 (incl. pad)
    fill0<<<8192, 256, 0, stream>>>((int4v*)aA, 2097152L);   // a = 0
    build_w<<<dim3(4, 2048), 256, 0, stream>>>(w, wT, wB, flag);

    for (int i = 0; i < 99; ++i) {
        gemm_nt<0, true, 128, 32, 8><<<dim3(64, 7), 512, 0, stream>>>(
            aA, wB, 784, 2048, 2048, 2048, x, nullptr, r, 800, flag);
        gemm_nt<1, false, 128, 32, 4><<<dim3(64, 16), 256, 0, stream>>>(
            r, wT, 2048, 800, 800, 800, nullptr, u, aA, 2048, flag);
    }

    gemm_nt<2, true, 128, 32, 8><<<dim3(64, 7), 512, 0, stream>>>(
        aA, wB, 784, 2048, 2048, 2048, nullptr, nullptr, rec, 784, flag);

    float* aOutF = (float*)d_out + 6422528;
    a_move<<<45312, 256, 0, stream>>>(aA, aOutF, 5177344L, 16777216L, flag);
    a_move<<<20224, 256, 0, stream>>>(aA, aOutF, 0L, 5177344L, flag);
    recon_out<<<25088, 256, 0, stream>>>(rec, d_out, flag);
}